// Round 1
// 632.896 us; speedup vs baseline: 1.0363x; 1.0363x over previous
//
#include <hip/hip_runtime.h>
#include <hip/hip_bf16.h>
#include <math.h>

// Problem constants (B=2,S=2048,D=1024,H=4096,E=8,K=2)
#define NTOK 4096
#define DD   1024
#define HH   4096
#define EE   8
#define NSLOT 8192          // NTOK * K (every token picks exactly 2 experts)
#define NSLOT_PAD 8448      // +256 rows so a 256-row tile never reads OOB
#define RBLK 128            // router blocks (32 tokens each)

typedef __bf16 bf16x8 __attribute__((ext_vector_type(8)));
typedef float  f32x4  __attribute__((ext_vector_type(4)));
typedef unsigned short u16x8 __attribute__((ext_vector_type(8)));

// s_waitcnt imm encoding (gfx9 family): vmcnt[3:0]+[15:14], expcnt[6:4], lgkmcnt[11:8]
#define WAITCNT_VM(n) (((n) & 0xF) | (0x7 << 4) | (0xF << 8) | (((n) >> 4) << 14))

// ---------------- ws layout (bytes) ----------------
#define WS_COUNTS     0
#define WS_CURSORS    64
#define WS_OFFSETS    128
#define WS_IMP        256
#define WS_TOPK_IDX   512
#define WS_TOPK_GATE  33280
#define WS_SLOT_OF    66048
#define WS_TOKEN_LIST 98816
// xg bf16 [8448][1024]         = 17,301,504 B
#define WS_XG         131584
// hbuf bf16 [8448][4096]       = 69,206,016 B  (rows >= 8192 are guard rows)
#define WS_HBUF       17433088
// ybuf f32 [8192][1024]        = 33,554,432 B
#define WS_YBUF       86639104
// W1bt bf16 [8][4096][1024]    = 67,108,864 B
#define WS_W1BT       120193536
// W2bt bf16 [8][1024][4096]    = 67,108,864 B
#define WS_W2BT       187302400
// total                        = 254,411,264 B (~242.6 MiB)
// Router partials live in hbuf's guard-row region (never stored by gemm1,
// read only as masked garbage by gemm2):
#define WS_CNT_PART   (WS_HBUF + (size_t)NSLOT * HH * 2)          // int[128*8]
#define WS_IMP_PART   (WS_HBUF + (size_t)NSLOT * HH * 2 + 4096)   // float[128*8]

__device__ __forceinline__ float gelu_exact(float v) {
    return 0.5f * v * (1.0f + erff(v * 0.70710678118654752f));
}

__device__ __forceinline__ void async_copy16(const __bf16* g, __bf16* l) {
    __builtin_amdgcn_global_load_lds(
        (const __attribute__((address_space(1))) void*)g,
        (__attribute__((address_space(3))) void*)l, 16, 0, 0);
}

// ---------------- Router: 8 lanes per token, no global atomics ----------
__launch_bounds__(256)
__global__ void router_kernel(const float* __restrict__ x,
                              const float* __restrict__ Wr,
                              const float* __restrict__ br,
                              int* __restrict__ cntPart,
                              float* __restrict__ impPart,
                              int* __restrict__ topk_idx,
                              float* __restrict__ topk_gate) {
    __shared__ float WrL[DD * EE];      // 32 KB
    __shared__ float impW[4][EE];
    __shared__ int cntL[EE];
    int tid = threadIdx.x;
    int lane = tid & 63, wave = tid >> 6;
    int grp = lane >> 3, e = lane & 7;
    int t = blockIdx.x * 32 + wave * 8 + grp;

    for (int i = tid; i < DD * EE / 4; i += 256)
        ((float4*)WrL)[i] = ((const float4*)Wr)[i];
    if (tid < EE) cntL[tid] = 0;
    __syncthreads();

    const float* xr = x + (size_t)t * DD;
    float acc = 0.f;
#pragma unroll 4
    for (int d = 0; d < DD; d += 4) {
        float4 xv = *(const float4*)(xr + d);
        acc = fmaf(xv.x, WrL[(d + 0) * EE + e], acc);
        acc = fmaf(xv.y, WrL[(d + 1) * EE + e], acc);
        acc = fmaf(xv.z, WrL[(d + 2) * EE + e], acc);
        acc = fmaf(xv.w, WrL[(d + 3) * EE + e], acc);
    }
    float l = acc + br[e];

    // softmax prob for (t,e) across the 8 lanes of this token
    float m = l;
#pragma unroll
    for (int mk = 1; mk <= 4; mk <<= 1) m = fmaxf(m, __shfl_xor(m, mk, 64));
    float p = expf(l - m);
    float s = p;
#pragma unroll
    for (int mk = 1; mk <= 4; mk <<= 1) s += __shfl_xor(s, mk, 64);
    p /= s;

    // top-1 argmax (ties -> lowest index, matching jax.lax.top_k)
    float bl = l; int be = e;
#pragma unroll
    for (int mk = 1; mk <= 4; mk <<= 1) {
        float ol = __shfl_xor(bl, mk, 64);
        int   oe = __shfl_xor(be, mk, 64);
        if (ol > bl || (ol == bl && oe < be)) { bl = ol; be = oe; }
    }
    int e1 = be; float l1 = bl;
    // top-2
    float cl = (e == e1) ? -INFINITY : l; int ce = e;
#pragma unroll
    for (int mk = 1; mk <= 4; mk <<= 1) {
        float ol = __shfl_xor(cl, mk, 64);
        int   oe = __shfl_xor(ce, mk, 64);
        if (ol > cl || (ol == cl && oe < ce)) { cl = ol; ce = oe; }
    }
    int e2 = ce; float l2 = cl;

    if (e == 0) {
        float bb = expf(l2 - l1);        // <= 1
        float g1 = 1.f / (1.f + bb);
        topk_idx[t * 2 + 0] = e1; topk_idx[t * 2 + 1] = e2;
        topk_gate[t * 2 + 0] = g1; topk_gate[t * 2 + 1] = bb * g1;
        atomicAdd(&cntL[e1], 1);         // LDS atomics only
        atomicAdd(&cntL[e2], 1);
    }

    // importance: sum p over the 8 token-groups in this wave
#pragma unroll
    for (int mk = 8; mk <= 32; mk <<= 1) p += __shfl_xor(p, mk, 64);
    if (lane < 8) impW[wave][lane] = p;
    __syncthreads();
    if (tid < EE) {
        float v = impW[0][tid] + impW[1][tid] + impW[2][tid] + impW[3][tid];
        impPart[blockIdx.x * EE + tid] = v;
        cntPart[blockIdx.x * EE + tid] = cntL[tid];
    }
}

// ---------------- Prefix: sum partials -> offsets/cursors + aux loss -------
__launch_bounds__(64)
__global__ void prefix_kernel(const int* __restrict__ cntPart,
                              const float* __restrict__ impPart,
                              int* __restrict__ offsets,
                              int* __restrict__ cursors,
                              float* __restrict__ aux_out) {
    __shared__ int cs[EE];
    __shared__ float is[EE];
    int tid = threadIdx.x;
    if (tid < EE) {
        int c = 0; float v = 0.f;
        for (int b = 0; b < RBLK; b++) {
            c += cntPart[b * EE + tid];
            v += impPart[b * EE + tid];
        }
        cs[tid] = c; is[tid] = v;
    }
    __syncthreads();
    if (tid == 0) {
        int o = 0;
        for (int e = 0; e < EE; e++) { offsets[e] = o; cursors[e] = o; o += cs[e]; }
        offsets[EE] = o;
        float aux = 0.f;
        for (int e = 0; e < EE; e++) {
            float d = is[e] / (float)NTOK - 1.0f / (float)EE;
            aux += d * d;
        }
        aux_out[0] = aux / (float)EE;
    }
}

// ---------------- Scatter: two-phase, 8 global atomics per block -----------
__launch_bounds__(256)
__global__ void scatter_kernel(const int* __restrict__ topk_idx,
                               int* __restrict__ cursors,
                               int* __restrict__ token_list,
                               int* __restrict__ slot_of) {
    __shared__ int lcnt[EE];
    __shared__ int lbase[EE];
    int tid = threadIdx.x;
    int t = blockIdx.x * 256 + tid;
    if (tid < EE) lcnt[tid] = 0;
    __syncthreads();
    int e0 = topk_idx[t * 2 + 0], e1 = topk_idx[t * 2 + 1];
    int r0 = atomicAdd(&lcnt[e0], 1);
    int r1 = atomicAdd(&lcnt[e1], 1);
    __syncthreads();
    if (tid < EE) lbase[tid] = atomicAdd(&cursors[tid], lcnt[tid]);
    __syncthreads();
    int s0 = lbase[e0] + r0, s1 = lbase[e1] + r1;
    token_list[s0] = t; token_list[s1] = t;
    slot_of[t * 2 + 0] = s0; slot_of[t * 2 + 1] = s1;
}

// ---------------- Gather x rows into packed bf16 slot rows ----------------
__launch_bounds__(256)
__global__ void gather_x_kernel(const float* __restrict__ x,
                                const int* __restrict__ token_list,
                                __bf16* __restrict__ xg) {
    int s = blockIdx.x;
    int t = token_list[s];
    int tid = threadIdx.x;           // 256 threads x float4 = 1024 elems
    float4 v = ((const float4*)(x + (size_t)t * DD))[tid];
    __bf16 tmp[4] __attribute__((aligned(8)));
    tmp[0] = (__bf16)v.x; tmp[1] = (__bf16)v.y;
    tmp[2] = (__bf16)v.z; tmp[3] = (__bf16)v.w;
    ((ushort4*)(xg + (size_t)s * DD))[tid] = *(ushort4*)tmp;
}

// ---------------- Weight convert+transpose: [E][R][C] f32 -> [E][C][R] bf16 ----
__launch_bounds__(256)
__global__ void transpose_w_kernel(const float* __restrict__ in,
                                   __bf16* __restrict__ out,
                                   int R, int C) {
    int e = blockIdx.z;
    int c0 = blockIdx.x * 64, r0 = blockIdx.y * 64;
    __shared__ float tile[64][65];
    int tid = threadIdx.x;
    const float* ip = in + (size_t)e * R * C;
#pragma unroll
    for (int i = 0; i < 4; i++) {
        int flat = i * 256 + tid;
        int r = flat >> 4, c4 = (flat & 15) * 4;
        float4 v = *(const float4*)(ip + (size_t)(r0 + r) * C + c0 + c4);
        tile[r][c4 + 0] = v.x; tile[r][c4 + 1] = v.y;
        tile[r][c4 + 2] = v.z; tile[r][c4 + 3] = v.w;
    }
    __syncthreads();
    __bf16* op = out + (size_t)e * C * R;
    // write side: 16B per lane (ushort8), 2 passes
#pragma unroll
    for (int i = 0; i < 2; i++) {
        int flat = i * 256 + tid;
        int c = flat >> 3, r8 = (flat & 7) * 8;
        __bf16 tmp[8] __attribute__((aligned(16)));
#pragma unroll
        for (int j = 0; j < 8; j++) tmp[j] = (__bf16)tile[r8 + j][c];
        *(u16x8*)(op + (size_t)(c0 + c) * R + r0 + r8) = *(u16x8*)tmp;
    }
}

// ---------------- Grouped GEMM, 256-wide tile, 8-wave phase-interleaved ----
// C[m][n] = A[m][:] . Bt[n][:].  A: bf16 [NSLOT_PAD][K] packed slot rows;
// Bt: bf16 [E][N][K].  BM=256, BK=64, 512 threads (8 waves).
//   BN=256: wave grid 2M x 4N (wave tile 128x64), 4 phases/K-tile, LDS 128KB
//   BN=128: wave grid 4M x 2N (wave tile  64x64), 2 phases/K-tile, LDS  96KB
// Interleaved wave->fragment mapping: frag row = (mi*WGM+wm)*16, so each
// phase (mh,nh) touches exactly one 128-row LDS half for EVERY wave ->
// per-phase half-granular counted vmcnt waits are valid.  Prefetch of K-tile
// t+1 is issued spread across tile t's phases; vmcnt never drains to 0 in
// the main loop (T3+T4).  s_setprio(1) wraps each 16-MFMA cluster (T5).
// XOR chunk swizzle (proven 0-bank-conflict): stage lane writes global
// col-chunk (lane&7)^(lane>>3); frag reads chunk (kchunk ^ (row&7)).
template <int N, int K, int BN, bool GELU, typename OutT>
__launch_bounds__(512, 2)
__global__ void gemm8p_kernel(const __bf16* __restrict__ A,
                              const __bf16* __restrict__ Bt,
                              const float* __restrict__ bias,
                              const int* __restrict__ offsets,
                              OutT* __restrict__ Out) {
    constexpr int BM  = 256;
    constexpr int NHB = BN / 128;            // B halves (2 or 1)
    constexpr int WGN = (BN == 256) ? 4 : 2; // wave grid N
    constexpr int WGM = 8 / WGN;             // wave grid M (2 or 4)
    constexpr int MF  = BM / (WGM * 16);     // per-wave M frags (8 or 4)
    constexpr int NF  = BN / (WGN * 16);     // per-wave N frags (4)
    constexpr int APF = MF / 2;              // A frags per phase (4 or 2)
    constexpr int BPF = (NHB == 2) ? 2 : NF; // B frags per MFMA phase
    constexpr int NT  = K / 64;

    int e = blockIdx.z, ct = blockIdx.x, rt = blockIdx.y;
    int obase = offsets[e], cnt = offsets[e + 1] - obase;
    int m0 = rt * BM;
    if (m0 >= cnt) return;

    __shared__ __bf16 As[2][2][16 * 512];     // [dbuf][half][chunk*512]
    __shared__ __bf16 Bs[2][NHB][16 * 512];

    int tid = threadIdx.x, lane = tid & 63, wave = tid >> 6;
    int quad = lane >> 4, m16 = lane & 15;
    int wm = wave & (WGM - 1), wn = wave / WGM;
    int srow = lane >> 3;                     // row within 8-row chunk
    int scol = ((lane & 7) ^ srow) * 8;       // swizzled bf16 col offset

    const __bf16* Ag = A + (size_t)(obase + m0) * K + scol;
    const __bf16* Bg = Bt + ((size_t)e * N + (size_t)ct * BN) * K + scol;

    // per-lane global src pointers: [half][chunk-pass r]; chunk = r*8+wave
    const __bf16* pA[2][2];
    const __bf16* pB[NHB][2];
#pragma unroll
    for (int h = 0; h < 2; h++)
#pragma unroll
        for (int r = 0; r < 2; r++)
            pA[h][r] = Ag + (size_t)(h * 128 + r * 64 + wave * 8 + srow) * K;
#pragma unroll
    for (int h = 0; h < NHB; h++)
#pragma unroll
        for (int r = 0; r < 2; r++)
            pB[h][r] = Bg + (size_t)(h * 128 + r * 64 + wave * 8 + srow) * K;

    f32x4 acc[MF][NF] = {};
    bf16x8 af[APF][2], bfr[NF][2];

#define STG_A(buf, h, k0)                                                     \
    { async_copy16(pA[h][0] + (k0), &As[buf][h][wave * 512]);                 \
      async_copy16(pA[h][1] + (k0), &As[buf][h][(wave + 8) * 512]); }
#define STG_B(buf, h, k0)                                                     \
    { async_copy16(pB[h][0] + (k0), &Bs[buf][h][wave * 512]);                 \
      async_copy16(pB[h][1] + (k0), &Bs[buf][h][(wave + 8) * 512]); }

#define READ_A(buf, mh)                                                       \
    { _Pragma("unroll")                                                       \
      for (int mi = 0; mi < APF; mi++) {                                      \
          int r = (mi * WGM + wm) * 16 + m16;                                 \
          const __bf16* bp = &As[buf][mh][(r >> 3) * 512 + (r & 7) * 64];     \
          af[mi][0] = *(const bf16x8*)(bp + ((quad ^ (r & 7)) * 8));          \
          af[mi][1] = *(const bf16x8*)(bp + (((4 + quad) ^ (r & 7)) * 8)); } }
#define READ_B(buf, nh, nn)                                                   \
    { _Pragma("unroll")                                                       \
      for (int ni = 0; ni < (nn); ni++) {                                     \
          int r = (ni * WGN + wn) * 16 + m16;                                 \
          const __bf16* bp = &Bs[buf][nh][(r >> 3) * 512 + (r & 7) * 64];     \
          bfr[(nh) * 2 + ni][0] = *(const bf16x8*)(bp + ((quad ^ (r & 7)) * 8)); \
          bfr[(nh) * 2 + ni][1] = *(const bf16x8*)(bp + (((4 + quad) ^ (r & 7)) * 8)); } }

#define MMA(mh, nh)                                                           \
    { __builtin_amdgcn_s_setprio(1);                                         \
      _Pragma("unroll")                                                       \
      for (int kk = 0; kk < 2; kk++)                                          \
          _Pragma("unroll")                                                   \
          for (int mi = 0; mi < APF; mi++)                                    \
              _Pragma("unroll")                                               \
              for (int ni = 0; ni < BPF; ni++)                                \
                  acc[(mh) * APF + mi][(nh) * 2 + ni] =                       \
                      __builtin_amdgcn_mfma_f32_16x16x32_bf16(                \
                          af[mi][kk], bfr[(nh) * 2 + ni][kk],                 \
                          acc[(mh) * APF + mi][(nh) * 2 + ni], 0, 0, 0);      \
      __builtin_amdgcn_s_setprio(0); }

    // prologue: stage K-tile 0, issue order A0,B0,[B1,]A1 (matches loop order)
    STG_A(0, 0, 0);
    STG_B(0, 0, 0);
    if constexpr (NHB == 2) STG_B(0, 1, 0);
    STG_A(0, 1, 0);

    int cur = 0;
    for (int t = 0; t < NT - 1; t++) {
        int k1 = (t + 1) * 64;
        int nxt = cur ^ 1;
        if constexpr (NHB == 2) {
            // P1: needs A-h0,B-h0 (oldest 4 of 8 outstanding)
            __builtin_amdgcn_s_waitcnt(WAITCNT_VM(4));
            __builtin_amdgcn_s_barrier();
            READ_A(cur, 0); READ_B(cur, 0, 2);
            STG_A(nxt, 0, k1); STG_B(nxt, 0, k1);
            MMA(0, 0);
            // P2: needs B-h1
            __builtin_amdgcn_s_waitcnt(WAITCNT_VM(6));
            __builtin_amdgcn_s_barrier();
            READ_B(cur, 1, 2);
            STG_B(nxt, 1, k1);
            MMA(0, 1);
            // P3: needs A-h1
            __builtin_amdgcn_s_waitcnt(WAITCNT_VM(6));
            __builtin_amdgcn_s_barrier();
            READ_A(cur, 1);
            STG_A(nxt, 1, k1);
            MMA(1, 1);
            // P4: all frags live, no new reads/stages/waits
            MMA(1, 0);
        } else {
            // P1: needs A-h0 + all of B (oldest 4 of 6 outstanding)
            __builtin_amdgcn_s_waitcnt(WAITCNT_VM(2));
            __builtin_amdgcn_s_barrier();
            READ_A(cur, 0); READ_B(cur, 0, 4);
            STG_A(nxt, 0, k1); STG_B(nxt, 0, k1);
            MMA(0, 0);
            // P2: needs A-h1
            __builtin_amdgcn_s_waitcnt(WAITCNT_VM(4));
            __builtin_amdgcn_s_barrier();
            READ_A(cur, 1);
            STG_A(nxt, 1, k1);
            MMA(1, 0);
        }
        cur = nxt;
    }
    // last K-tile: no prefetch, draining waits
    if constexpr (NHB == 2) {
        __builtin_amdgcn_s_waitcnt(WAITCNT_VM(4));
        __builtin_amdgcn_s_barrier();
        READ_A(cur, 0); READ_B(cur, 0, 2);
        MMA(0, 0);
        __builtin_amdgcn_s_waitcnt(WAITCNT_VM(2));
        __builtin_amdgcn_s_barrier();
        READ_B(cur, 1, 2);
        MMA(0, 1);
        __builtin_amdgcn_s_waitcnt(WAITCNT_VM(0));
        __builtin_amdgcn_s_barrier();
        READ_A(cur, 1);
        MMA(1, 1);
        MMA(1, 0);
    } else {
        __builtin_amdgcn_s_waitcnt(WAITCNT_VM(2));
        __builtin_amdgcn_s_barrier();
        READ_A(cur, 0); READ_B(cur, 0, 4);
        MMA(0, 0);
        __builtin_amdgcn_s_waitcnt(WAITCNT_VM(0));
        __builtin_amdgcn_s_barrier();
        READ_A(cur, 1);
        MMA(1, 0);
    }
#undef STG_A
#undef STG_B
#undef READ_A
#undef READ_B
#undef MMA

    // epilogue: +bias, optional gelu, masked store
    float bv[NF];
#pragma unroll
    for (int ni = 0; ni < NF; ni++)
        bv[ni] = bias[(size_t)e * N + ct * BN + (ni * WGN + wn) * 16 + m16];
#pragma unroll
    for (int mi = 0; mi < MF; mi++) {
#pragma unroll
        for (int rr = 0; rr < 4; rr++) {
            int row = (mi * WGM + wm) * 16 + quad * 4 + rr;
            if (m0 + row < cnt) {
                size_t orow = (size_t)(obase + m0 + row) * N + (size_t)ct * BN;
#pragma unroll
                for (int ni = 0; ni < NF; ni++) {
                    float v = acc[mi][ni][rr] + bv[ni];
                    if (GELU) v = gelu_exact(v);
                    Out[orow + (ni * WGN + wn) * 16 + m16] = (OutT)v;
                }
            }
        }
    }
}

// ---------------- Combine: out[t] = g0*y[s0] + g1*y[s1] ----------------
__launch_bounds__(256)
__global__ void combine_kernel(const float* __restrict__ ybuf,
                               const int* __restrict__ slot_of,
                               const float* __restrict__ topk_gate,
                               float* __restrict__ out) {
    int t = blockIdx.x;
    int tid = threadIdx.x;
    int s0 = slot_of[t * 2 + 0], s1 = slot_of[t * 2 + 1];
    float g0 = topk_gate[t * 2 + 0], g1 = topk_gate[t * 2 + 1];
    const float4* y0 = (const float4*)(ybuf + (size_t)s0 * DD);
    const float4* y1 = (const float4*)(ybuf + (size_t)s1 * DD);
    float4 a = y0[tid], b = y1[tid];
    float4 o;
    o.x = g0 * a.x + g1 * b.x;
    o.y = g0 * a.y + g1 * b.y;
    o.z = g0 * a.z + g1 * b.z;
    o.w = g0 * a.w + g1 * b.w;
    ((float4*)(out + (size_t)t * DD))[tid] = o;
}

extern "C" void kernel_launch(void* const* d_in, const int* in_sizes, int n_in,
                              void* d_out, int out_size, void* d_ws, size_t ws_size,
                              hipStream_t stream) {
    const float* x  = (const float*)d_in[0];
    const float* Wr = (const float*)d_in[1];
    const float* br = (const float*)d_in[2];
    const float* W1 = (const float*)d_in[3];
    const float* b1 = (const float*)d_in[4];
    const float* W2 = (const float*)d_in[5];
    const float* b2 = (const float*)d_in[6];
    float* out = (float*)d_out;

    char* ws = (char*)d_ws;
    int*    offsets    = (int*)(ws + WS_OFFSETS);
    int*    cursors    = (int*)(ws + WS_CURSORS);
    int*    topk_idx   = (int*)(ws + WS_TOPK_IDX);
    float*  topk_gate  = (float*)(ws + WS_TOPK_GATE);
    int*    slot_of    = (int*)(ws + WS_SLOT_OF);
    int*    token_list = (int*)(ws + WS_TOKEN_LIST);
    __bf16* xg         = (__bf16*)(ws + WS_XG);
    __bf16* hbuf       = (__bf16*)(ws + WS_HBUF);
    float*  ybuf       = (float*)(ws + WS_YBUF);
    __bf16* W1bt       = (__bf16*)(ws + WS_W1BT);
    __bf16* W2bt       = (__bf16*)(ws + WS_W2BT);
    int*    cntPart    = (int*)(ws + WS_CNT_PART);
    float*  impPart    = (float*)(ws + WS_IMP_PART);

    router_kernel<<<RBLK, 256, 0, stream>>>(x, Wr, br, cntPart, impPart, topk_idx, topk_gate);
    prefix_kernel<<<1, 64, 0, stream>>>(cntPart, impPart, offsets, cursors, out + (size_t)NTOK * DD);
    scatter_kernel<<<NTOK / 256, 256, 0, stream>>>(topk_idx, cursors, token_list, slot_of);
    gather_x_kernel<<<NSLOT, 256, 0, stream>>>(x, token_list, xg);

    // W1 [E][D=1024][H=4096] -> W1bt [E][H][D];  W2 [E][H=4096][D=1024] -> W2bt [E][D][H]
    transpose_w_kernel<<<dim3(HH / 64, DD / 64, EE), 256, 0, stream>>>(W1, W1bt, DD, HH);
    transpose_w_kernel<<<dim3(DD / 64, HH / 64, EE), 256, 0, stream>>>(W2, W2bt, HH, DD);

    // Stage 1: hbuf = gelu(xg @ W1 + b1)   [slots x 4096]; BM=256,BN=256
    gemm8p_kernel<HH, DD, 256, true, __bf16>
        <<<dim3(HH / 256, 16, EE), 512, 0, stream>>>(xg, W1bt, b1, offsets, hbuf);
    // Stage 2: ybuf = hbuf @ W2 + b2       [slots x 1024]; BM=256,BN=128
    gemm8p_kernel<DD, HH, 128, false, float>
        <<<dim3(DD / 128, 16, EE), 512, 0, stream>>>(hbuf, W2bt, b2, offsets, ybuf);

    combine_kernel<<<NTOK, 256, 0, stream>>>(ybuf, slot_of, topk_gate, out);
}

// Round 2
// 622.436 us; speedup vs baseline: 1.0537x; 1.0168x over previous
//
#include <hip/hip_runtime.h>
#include <hip/hip_bf16.h>
#include <math.h>

// Problem constants (B=2,S=2048,D=1024,H=4096,E=8,K=2)
#define NTOK 4096
#define DD   1024
#define HH   4096
#define EE   8
#define NSLOT 8192          // NTOK * K (every token picks exactly 2 experts)
#define NSLOT_PAD 8448      // +256 guard rows so a row tile never reads OOB
#define RBLK 128            // router blocks (32 tokens each)

typedef __bf16 bf16x8 __attribute__((ext_vector_type(8)));
typedef float  f32x4  __attribute__((ext_vector_type(4)));
typedef unsigned short u16x8 __attribute__((ext_vector_type(8)));

// s_waitcnt imm encoding (gfx9 family): vmcnt[3:0]+[15:14], expcnt[6:4], lgkmcnt[11:8]
#define WAITCNT_VM(n) (((n) & 0xF) | (0x7 << 4) | (0xF << 8) | (((n) >> 4) << 14))

// ---------------- ws layout (bytes) ----------------
#define WS_COUNTS     0
#define WS_CURSORS    64
#define WS_OFFSETS    128
#define WS_IMP        256
#define WS_TOPK_IDX   512
#define WS_TOPK_GATE  33280
#define WS_SLOT_OF    66048
#define WS_TOKEN_LIST 98816
// xg bf16 [8448][1024]         = 17,301,504 B
#define WS_XG         131584
// hbuf bf16 [8448][4096]       = 69,206,016 B  (rows >= 8192 are guard rows)
#define WS_HBUF       17433088
// ybuf f32 [8192][1024]        = 33,554,432 B
#define WS_YBUF       86639104
// W1bt bf16 [8][4096][1024]    = 67,108,864 B
#define WS_W1BT       120193536
// W2bt bf16 [8][1024][4096]    = 67,108,864 B
#define WS_W2BT       187302400
// total                        = 254,411,264 B (~242.6 MiB)
// Router partials live in hbuf's guard-row region (never stored by gemm1,
// read only as masked garbage by gemm2):
#define WS_CNT_PART   (WS_HBUF + (size_t)NSLOT * HH * 2)          // int[128*8]
#define WS_IMP_PART   (WS_HBUF + (size_t)NSLOT * HH * 2 + 4096)   // float[128*8]

__device__ __forceinline__ float gelu_exact(float v) {
    return 0.5f * v * (1.0f + erff(v * 0.70710678118654752f));
}

__device__ __forceinline__ void async_copy16(const __bf16* g, __bf16* l) {
    __builtin_amdgcn_global_load_lds(
        (const __attribute__((address_space(1))) void*)g,
        (__attribute__((address_space(3))) void*)l, 16, 0, 0);
}

// ---------------- Router: 8 lanes per token, no global atomics ----------
__launch_bounds__(256)
__global__ void router_kernel(const float* __restrict__ x,
                              const float* __restrict__ Wr,
                              const float* __restrict__ br,
                              int* __restrict__ cntPart,
                              float* __restrict__ impPart,
                              int* __restrict__ topk_idx,
                              float* __restrict__ topk_gate) {
    __shared__ float WrL[DD * EE];      // 32 KB
    __shared__ float impW[4][EE];
    __shared__ int cntL[EE];
    int tid = threadIdx.x;
    int lane = tid & 63, wave = tid >> 6;
    int grp = lane >> 3, e = lane & 7;
    int t = blockIdx.x * 32 + wave * 8 + grp;

    for (int i = tid; i < DD * EE / 4; i += 256)
        ((float4*)WrL)[i] = ((const float4*)Wr)[i];
    if (tid < EE) cntL[tid] = 0;
    __syncthreads();

    const float* xr = x + (size_t)t * DD;
    float acc = 0.f;
#pragma unroll 4
    for (int d = 0; d < DD; d += 4) {
        float4 xv = *(const float4*)(xr + d);
        acc = fmaf(xv.x, WrL[(d + 0) * EE + e], acc);
        acc = fmaf(xv.y, WrL[(d + 1) * EE + e], acc);
        acc = fmaf(xv.z, WrL[(d + 2) * EE + e], acc);
        acc = fmaf(xv.w, WrL[(d + 3) * EE + e], acc);
    }
    float l = acc + br[e];

    // softmax prob for (t,e) across the 8 lanes of this token
    float m = l;
#pragma unroll
    for (int mk = 1; mk <= 4; mk <<= 1) m = fmaxf(m, __shfl_xor(m, mk, 64));
    float p = expf(l - m);
    float s = p;
#pragma unroll
    for (int mk = 1; mk <= 4; mk <<= 1) s += __shfl_xor(s, mk, 64);
    p /= s;

    // top-1 argmax (ties -> lowest index, matching jax.lax.top_k)
    float bl = l; int be = e;
#pragma unroll
    for (int mk = 1; mk <= 4; mk <<= 1) {
        float ol = __shfl_xor(bl, mk, 64);
        int   oe = __shfl_xor(be, mk, 64);
        if (ol > bl || (ol == bl && oe < be)) { bl = ol; be = oe; }
    }
    int e1 = be; float l1 = bl;
    // top-2
    float cl = (e == e1) ? -INFINITY : l; int ce = e;
#pragma unroll
    for (int mk = 1; mk <= 4; mk <<= 1) {
        float ol = __shfl_xor(cl, mk, 64);
        int   oe = __shfl_xor(ce, mk, 64);
        if (ol > cl || (ol == cl && oe < ce)) { cl = ol; ce = oe; }
    }
    int e2 = ce; float l2 = cl;

    if (e == 0) {
        float bb = expf(l2 - l1);        // <= 1
        float g1 = 1.f / (1.f + bb);
        topk_idx[t * 2 + 0] = e1; topk_idx[t * 2 + 1] = e2;
        topk_gate[t * 2 + 0] = g1; topk_gate[t * 2 + 1] = bb * g1;
        atomicAdd(&cntL[e1], 1);         // LDS atomics only
        atomicAdd(&cntL[e2], 1);
    }

    // importance: sum p over the 8 token-groups in this wave
#pragma unroll
    for (int mk = 8; mk <= 32; mk <<= 1) p += __shfl_xor(p, mk, 64);
    if (lane < 8) impW[wave][lane] = p;
    __syncthreads();
    if (tid < EE) {
        float v = impW[0][tid] + impW[1][tid] + impW[2][tid] + impW[3][tid];
        impPart[blockIdx.x * EE + tid] = v;
        cntPart[blockIdx.x * EE + tid] = cntL[tid];
    }
}

// ---------------- Prefix: sum partials -> offsets/cursors + aux loss -------
__launch_bounds__(64)
__global__ void prefix_kernel(const int* __restrict__ cntPart,
                              const float* __restrict__ impPart,
                              int* __restrict__ offsets,
                              int* __restrict__ cursors,
                              float* __restrict__ aux_out) {
    __shared__ int cs[EE];
    __shared__ float is[EE];
    int tid = threadIdx.x;
    if (tid < EE) {
        int c = 0; float v = 0.f;
        for (int b = 0; b < RBLK; b++) {
            c += cntPart[b * EE + tid];
            v += impPart[b * EE + tid];
        }
        cs[tid] = c; is[tid] = v;
    }
    __syncthreads();
    if (tid == 0) {
        int o = 0;
        for (int e = 0; e < EE; e++) { offsets[e] = o; cursors[e] = o; o += cs[e]; }
        offsets[EE] = o;
        float aux = 0.f;
        for (int e = 0; e < EE; e++) {
            float d = is[e] / (float)NTOK - 1.0f / (float)EE;
            aux += d * d;
        }
        aux_out[0] = aux / (float)EE;
    }
}

// ---------------- Scatter: two-phase, 8 global atomics per block -----------
__launch_bounds__(256)
__global__ void scatter_kernel(const int* __restrict__ topk_idx,
                               int* __restrict__ cursors,
                               int* __restrict__ token_list,
                               int* __restrict__ slot_of) {
    __shared__ int lcnt[EE];
    __shared__ int lbase[EE];
    int tid = threadIdx.x;
    int t = blockIdx.x * 256 + tid;
    if (tid < EE) lcnt[tid] = 0;
    __syncthreads();
    int e0 = topk_idx[t * 2 + 0], e1 = topk_idx[t * 2 + 1];
    int r0 = atomicAdd(&lcnt[e0], 1);
    int r1 = atomicAdd(&lcnt[e1], 1);
    __syncthreads();
    if (tid < EE) lbase[tid] = atomicAdd(&cursors[tid], lcnt[tid]);
    __syncthreads();
    int s0 = lbase[e0] + r0, s1 = lbase[e1] + r1;
    token_list[s0] = t; token_list[s1] = t;
    slot_of[t * 2 + 0] = s0; slot_of[t * 2 + 1] = s1;
}

// ---------------- Gather x rows into packed bf16 slot rows ----------------
__launch_bounds__(256)
__global__ void gather_x_kernel(const float* __restrict__ x,
                                const int* __restrict__ token_list,
                                __bf16* __restrict__ xg) {
    int s = blockIdx.x;
    int t = token_list[s];
    int tid = threadIdx.x;           // 256 threads x float4 = 1024 elems
    float4 v = ((const float4*)(x + (size_t)t * DD))[tid];
    __bf16 tmp[4] __attribute__((aligned(8)));
    tmp[0] = (__bf16)v.x; tmp[1] = (__bf16)v.y;
    tmp[2] = (__bf16)v.z; tmp[3] = (__bf16)v.w;
    ((ushort4*)(xg + (size_t)s * DD))[tid] = *(ushort4*)tmp;
}

// ---------------- Weight convert+transpose: [E][R][C] f32 -> [E][C][R] bf16 ----
__launch_bounds__(256)
__global__ void transpose_w_kernel(const float* __restrict__ in,
                                   __bf16* __restrict__ out,
                                   int R, int C) {
    int e = blockIdx.z;
    int c0 = blockIdx.x * 64, r0 = blockIdx.y * 64;
    __shared__ float tile[64][65];
    int tid = threadIdx.x;
    const float* ip = in + (size_t)e * R * C;
#pragma unroll
    for (int i = 0; i < 4; i++) {
        int flat = i * 256 + tid;
        int r = flat >> 4, c4 = (flat & 15) * 4;
        float4 v = *(const float4*)(ip + (size_t)(r0 + r) * C + c0 + c4);
        tile[r][c4 + 0] = v.x; tile[r][c4 + 1] = v.y;
        tile[r][c4 + 2] = v.z; tile[r][c4 + 3] = v.w;
    }
    __syncthreads();
    __bf16* op = out + (size_t)e * C * R;
    // write side: 16B per lane (ushort8), 2 passes
#pragma unroll
    for (int i = 0; i < 2; i++) {
        int flat = i * 256 + tid;
        int c = flat >> 3, r8 = (flat & 7) * 8;
        __bf16 tmp[8] __attribute__((aligned(16)));
#pragma unroll
        for (int j = 0; j < 8; j++) tmp[j] = (__bf16)tile[r8 + j][c];
        *(u16x8*)(op + (size_t)(c0 + c) * R + r0 + r8) = *(u16x8*)tmp;
    }
}

// ---------------- Grouped GEMM: 128x128 tile, BK=64, 2 blocks/CU ----------
// C[m][n] = A[m][:] . Bt[n][:].  A: bf16 [NSLOT_PAD][K] packed slot rows;
// Bt: bf16 [E][N][K].  512 threads = 8 waves in a 4(M) x 2(N) grid; each
// wave owns a 32x64 sub-tile (MF=2 interleaved row frags, NF=4 col frags).
// 64 KB LDS -> 2 blocks/CU (16 waves): the co-resident block covers
// barrier/vmcnt stalls.  Per K-tile: 4 global_load_lds per thread
// (A-h0, B, B, A-h1); 2 phases with counted vmcnt (1 then 3) that never
// drain mid-loop; s_setprio(1) around each 8-MFMA cluster.
// XOR chunk swizzle (0 bank conflicts): stage lane writes global col-chunk
// (lane&7)^(lane>>3); fragment reads chunk (kchunk ^ (row&7)).
template <int N, int K, bool GELU, typename OutT>
__launch_bounds__(512, 4)
__global__ void gemm128_kernel(const __bf16* __restrict__ A,
                               const __bf16* __restrict__ Bt,
                               const float* __restrict__ bias,
                               const int* __restrict__ offsets,
                               OutT* __restrict__ Out) {
    constexpr int NT = K / 64;
    int e = blockIdx.z, ct = blockIdx.x, rt = blockIdx.y;
    int obase = offsets[e], cnt = offsets[e + 1] - obase;
    int m0 = rt * 128;
    if (m0 >= cnt) return;

    __shared__ __bf16 As[2][2][8 * 512];   // [dbuf][half: rows 0-63 / 64-127]
    __shared__ __bf16 Bs[2][16 * 512];     // [dbuf] 128 rows x 64 K

    int tid = threadIdx.x, lane = tid & 63, wave = tid >> 6;
    int quad = lane >> 4, m16 = lane & 15;
    int wm = wave & 3, wn = wave >> 2;     // 4 x 2 wave grid
    int srow = lane >> 3;                  // row within 8-row chunk
    int scol = ((lane & 7) ^ srow) * 8;    // swizzled bf16 col offset

    const __bf16* Ag = A + (size_t)(obase + m0) * K + scol;
    const __bf16* Bg = Bt + ((size_t)e * N + (size_t)ct * 128) * K + scol;

    // per-lane global src pointers
    const __bf16* pA[2];                   // A half h: rows h*64 + wave*8+srow
    const __bf16* pB[2];                   // B pass p: rows p*64 + wave*8+srow
#pragma unroll
    for (int h = 0; h < 2; h++) pA[h] = Ag + (size_t)(h * 64 + wave * 8 + srow) * K;
#pragma unroll
    for (int p = 0; p < 2; p++) pB[p] = Bg + (size_t)(p * 64 + wave * 8 + srow) * K;

    // fragment LDS read bases (element offsets); swz key = m16&7 for all frags
    int swz = m16 & 7;
    int abase = (wm * 2 + (m16 >> 3)) * 512 + swz * 64;          // local row wm*16+m16
    int bbase[4];
#pragma unroll
    for (int ni = 0; ni < 4; ni++)
        bbase[ni] = (ni * 4 + wn * 2 + (m16 >> 3)) * 512 + swz * 64;  // row (ni*2+wn)*16+m16

    f32x4 acc[2][4] = {};
    bf16x8 af[2], bfr[4][2];

#define STG_A(buf, h, k0) async_copy16(pA[h] + (k0), &As[buf][h][wave * 512]);
#define STG_B(buf, k0)                                                        \
    { async_copy16(pB[0] + (k0), &Bs[buf][wave * 512]);                       \
      async_copy16(pB[1] + (k0), &Bs[buf][(wave + 8) * 512]); }

#define READ_A(buf, h)                                                        \
    { af[0] = *(const bf16x8*)(&As[buf][h][abase] + ((quad ^ swz) * 8));      \
      af[1] = *(const bf16x8*)(&As[buf][h][abase] + (((4 + quad) ^ swz) * 8)); }
#define READ_B(buf)                                                           \
    { _Pragma("unroll")                                                       \
      for (int ni = 0; ni < 4; ni++) {                                        \
          bfr[ni][0] = *(const bf16x8*)(&Bs[buf][bbase[ni]] + ((quad ^ swz) * 8)); \
          bfr[ni][1] = *(const bf16x8*)(&Bs[buf][bbase[ni]] + (((4 + quad) ^ swz) * 8)); } }

#define MMA(h)                                                                \
    { __builtin_amdgcn_s_setprio(1);                                         \
      _Pragma("unroll")                                                       \
      for (int kk = 0; kk < 2; kk++)                                          \
          _Pragma("unroll")                                                   \
          for (int ni = 0; ni < 4; ni++)                                      \
              acc[h][ni] = __builtin_amdgcn_mfma_f32_16x16x32_bf16(           \
                  af[kk], bfr[ni][kk], acc[h][ni], 0, 0, 0);                  \
      __builtin_amdgcn_s_setprio(0); }

    // prologue: stage K-tile 0; issue order A0, B, B, A1 (P1 needs A0+B)
    STG_A(0, 0, 0);
    STG_B(0, 0);
    STG_A(0, 1, 0);

    int cur = 0;
    for (int t = 0; t < NT - 1; t++) {
        int k1 = (t + 1) * 64, nxt = cur ^ 1;
        // P1: needs A-h0(t) + B(t); leaves A-h1(t) in flight
        __builtin_amdgcn_s_waitcnt(WAITCNT_VM(1));
        __builtin_amdgcn_s_barrier();
        READ_A(cur, 0); READ_B(cur);
        STG_A(nxt, 0, k1); STG_B(nxt, k1);
        MMA(0);
        // P2: needs A-h1(t); leaves t+1's A0,B,B (3) in flight
        __builtin_amdgcn_s_waitcnt(WAITCNT_VM(3));
        __builtin_amdgcn_s_barrier();
        READ_A(cur, 1);
        STG_A(nxt, 1, k1);
        MMA(1);
        cur = nxt;
    }
    // last K-tile: no prefetch, draining waits
    __builtin_amdgcn_s_waitcnt(WAITCNT_VM(1));
    __builtin_amdgcn_s_barrier();
    READ_A(cur, 0); READ_B(cur);
    MMA(0);
    __builtin_amdgcn_s_waitcnt(WAITCNT_VM(0));
    __builtin_amdgcn_s_barrier();
    READ_A(cur, 1);
    MMA(1);
#undef STG_A
#undef STG_B
#undef READ_A
#undef READ_B
#undef MMA

    // epilogue: +bias, optional gelu, masked store
    float bv[4];
#pragma unroll
    for (int ni = 0; ni < 4; ni++)
        bv[ni] = bias[(size_t)e * N + ct * 128 + (ni * 2 + wn) * 16 + m16];
#pragma unroll
    for (int mi = 0; mi < 2; mi++) {
#pragma unroll
        for (int rr = 0; rr < 4; rr++) {
            int row = (mi * 4 + wm) * 16 + quad * 4 + rr;
            if (m0 + row < cnt) {
                size_t orow = (size_t)(obase + m0 + row) * N + (size_t)ct * 128;
#pragma unroll
                for (int ni = 0; ni < 4; ni++) {
                    float v = acc[mi][ni][rr] + bv[ni];
                    if (GELU) v = gelu_exact(v);
                    Out[orow + (ni * 2 + wn) * 16 + m16] = (OutT)v;
                }
            }
        }
    }
}

// ---------------- Combine: out[t] = g0*y[s0] + g1*y[s1] ----------------
__launch_bounds__(256)
__global__ void combine_kernel(const float* __restrict__ ybuf,
                               const int* __restrict__ slot_of,
                               const float* __restrict__ topk_gate,
                               float* __restrict__ out) {
    int t = blockIdx.x;
    int tid = threadIdx.x;
    int s0 = slot_of[t * 2 + 0], s1 = slot_of[t * 2 + 1];
    float g0 = topk_gate[t * 2 + 0], g1 = topk_gate[t * 2 + 1];
    const float4* y0 = (const float4*)(ybuf + (size_t)s0 * DD);
    const float4* y1 = (const float4*)(ybuf + (size_t)s1 * DD);
    float4 a = y0[tid], b = y1[tid];
    float4 o;
    o.x = g0 * a.x + g1 * b.x;
    o.y = g0 * a.y + g1 * b.y;
    o.z = g0 * a.z + g1 * b.z;
    o.w = g0 * a.w + g1 * b.w;
    ((float4*)(out + (size_t)t * DD))[tid] = o;
}

extern "C" void kernel_launch(void* const* d_in, const int* in_sizes, int n_in,
                              void* d_out, int out_size, void* d_ws, size_t ws_size,
                              hipStream_t stream) {
    const float* x  = (const float*)d_in[0];
    const float* Wr = (const float*)d_in[1];
    const float* br = (const float*)d_in[2];
    const float* W1 = (const float*)d_in[3];
    const float* b1 = (const float*)d_in[4];
    const float* W2 = (const float*)d_in[5];
    const float* b2 = (const float*)d_in[6];
    float* out = (float*)d_out;

    char* ws = (char*)d_ws;
    int*    offsets    = (int*)(ws + WS_OFFSETS);
    int*    cursors    = (int*)(ws + WS_CURSORS);
    int*    topk_idx   = (int*)(ws + WS_TOPK_IDX);
    float*  topk_gate  = (float*)(ws + WS_TOPK_GATE);
    int*    slot_of    = (int*)(ws + WS_SLOT_OF);
    int*    token_list = (int*)(ws + WS_TOKEN_LIST);
    __bf16* xg         = (__bf16*)(ws + WS_XG);
    __bf16* hbuf       = (__bf16*)(ws + WS_HBUF);
    float*  ybuf       = (float*)(ws + WS_YBUF);
    __bf16* W1bt       = (__bf16*)(ws + WS_W1BT);
    __bf16* W2bt       = (__bf16*)(ws + WS_W2BT);
    int*    cntPart    = (int*)(ws + WS_CNT_PART);
    float*  impPart    = (float*)(ws + WS_IMP_PART);

    router_kernel<<<RBLK, 256, 0, stream>>>(x, Wr, br, cntPart, impPart, topk_idx, topk_gate);
    prefix_kernel<<<1, 64, 0, stream>>>(cntPart, impPart, offsets, cursors, out + (size_t)NTOK * DD);
    scatter_kernel<<<NTOK / 256, 256, 0, stream>>>(topk_idx, cursors, token_list, slot_of);
    gather_x_kernel<<<NSLOT, 256, 0, stream>>>(x, token_list, xg);

    // W1 [E][D=1024][H=4096] -> W1bt [E][H][D];  W2 [E][H=4096][D=1024] -> W2bt [E][D][H]
    transpose_w_kernel<<<dim3(HH / 64, DD / 64, EE), 256, 0, stream>>>(W1, W1bt, DD, HH);
    transpose_w_kernel<<<dim3(DD / 64, HH / 64, EE), 256, 0, stream>>>(W2, W2bt, HH, DD);

    // Stage 1: hbuf = gelu(xg @ W1 + b1)   [slots x 4096]
    gemm128_kernel<HH, DD, true, __bf16>
        <<<dim3(HH / 128, 32, EE), 512, 0, stream>>>(xg, W1bt, b1, offsets, hbuf);
    // Stage 2: ybuf = hbuf @ W2 + b2       [slots x 1024]
    gemm128_kernel<DD, HH, false, float>
        <<<dim3(DD / 128, 32, EE), 512, 0, stream>>>(hbuf, W2bt, b2, offsets, ybuf);

    combine_kernel<<<NTOK, 256, 0, stream>>>(ybuf, slot_of, topk_gate, out);
}